// Round 1
// 1775.567 us; speedup vs baseline: 1.2039x; 1.2039x over previous
//
#include <hip/hip_runtime.h>
#include <hip/hip_bf16.h>
#include <stdint.h>

#define Bn 4
#define Sn 2048
#define Dn 1024
#define Hn 16
#define DHn 64
#define En 16
#define In 1024
#define Tn 8192   // B*S

typedef float f32x4 __attribute__((ext_vector_type(4)));
typedef __bf16 bf16x8 __attribute__((ext_vector_type(8)));
typedef _Float16 f16;
typedef _Float16 f16x8 __attribute__((ext_vector_type(8)));
typedef unsigned short u16;
typedef unsigned int u32;

__device__ __forceinline__ u16 f2u(float f) {
    __bf16 h = (__bf16)f;
    return __builtin_bit_cast(u16, h);
}
__device__ __forceinline__ float u2f(u16 u) {
    return (float)__builtin_bit_cast(__bf16, u);
}
__device__ __forceinline__ u16 f2h(float f) {
    f16 h = (f16)f;
    return __builtin_bit_cast(u16, h);
}
__device__ __forceinline__ f32x4 mfma16(bf16x8 a, bf16x8 b, f32x4 c) {
    return __builtin_amdgcn_mfma_f32_16x16x32_bf16(a, b, c, 0, 0, 0);
}
__device__ __forceinline__ f32x4 mfma16h(f16x8 a, f16x8 b, f32x4 c) {
    return __builtin_amdgcn_mfma_f32_16x16x32_f16(a, b, c, 0, 0, 0);
}
__device__ __forceinline__ void splitf(float f, u16& h, u16& l) {
    f16 hh = (f16)f;
    f16 ll = (f16)(f - (float)hh);
    h = __builtin_bit_cast(u16, hh);
    l = __builtin_bit_cast(u16, ll);
}
__device__ __forceinline__ int imin(int a, int b) { return a < b ? a : b; }

// ---------------------------------------------------------------- zero meta
__global__ void k_zero(int* cnt) {
    if (threadIdx.x < En) cnt[threadIdx.x] = 0;
}

// ---------------------------------------------------------------- fp64 RoPE table: cos/sin [S][32]
__global__ void k_ropetab(float* __restrict__ ct, float* __restrict__ st) {
    int i = blockIdx.x * 256 + threadIdx.x;  // 65536 entries
    int s = i >> 5, j = i & 31;
    double inv = pow(10000.0, -(double)j / 32.0);
    double ang = (double)s * inv;
    ct[i] = (float)cos(ang);
    st[i] = (float)sin(ang);
}

// ---------------------------------------------------------------- rmsnorm (fp32 in -> fp32 or bf16 out)
template <bool BFOUT>
__global__ void k_rmsnorm(const float* __restrict__ x, const float* __restrict__ w,
                          void* __restrict__ outv) {
    int t = blockIdx.x;
    const float4* xr = (const float4*)(x + (long long)t * Dn);
    float4 v = xr[threadIdx.x];
    float ss = v.x * v.x + v.y * v.y + v.z * v.z + v.w * v.w;
    ss += __shfl_xor(ss, 1);  ss += __shfl_xor(ss, 2);  ss += __shfl_xor(ss, 4);
    ss += __shfl_xor(ss, 8);  ss += __shfl_xor(ss, 16); ss += __shfl_xor(ss, 32);
    __shared__ float sred[4];
    int lane = threadIdx.x & 63, wvi = threadIdx.x >> 6;
    if (lane == 0) sred[wvi] = ss;
    __syncthreads();
    float tot = sred[0] + sred[1] + sred[2] + sred[3];
    float sc = rsqrtf(tot * (1.f / Dn) + 1e-6f);
    const float4* wr = (const float4*)w;
    float4 w4 = wr[threadIdx.x];
    if constexpr (BFOUT) {
        u16 o4[4] = { f2u(v.x * sc * w4.x), f2u(v.y * sc * w4.y),
                      f2u(v.z * sc * w4.z), f2u(v.w * sc * w4.w) };
        ((uint2*)((u16*)outv + (long long)t * Dn))[threadIdx.x] = *(uint2*)o4;
    } else {
        float4 o = { v.x * sc * w4.x, v.y * sc * w4.y, v.z * sc * w4.z, v.w * sc * w4.w };
        ((float4*)((float*)outv + (long long)t * Dn))[threadIdx.x] = o;
    }
}

// ---------------------------------------------------------------- fp32-accurate GEMM via split-f16 (NT): C[M,N]=A[M,K]@B[N,K]^T
// EPI 0: fp32 store. EPI 1: fp32 store + residual add.
template <int EPI>
__global__ __launch_bounds__(256, 2) void k_gemm32(
    const float* __restrict__ A, const float* __restrict__ B,
    float* __restrict__ C, const float* __restrict__ resid,
    int K, int ldc, int ccol0) {
    constexpr int LDT = 40;
    __shared__ __align__(16) u16 sAh[128][LDT], sAl[128][LDT];
    __shared__ __align__(16) u16 sBh[128][LDT], sBl[128][LDT];
    int tid = threadIdx.x, lane = tid & 63, wvi = tid >> 6;
    int l16 = lane & 15, kg = lane >> 4;
    int n0 = blockIdx.x * 128, m0 = blockIdx.y * 128;
    int wrow = (wvi >> 1) * 64, wcol = (wvi & 1) * 64;
    f32x4 z = {0.f, 0.f, 0.f, 0.f};
    f32x4 acc[4][4];
    #pragma unroll
    for (int mi = 0; mi < 4; mi++)
        #pragma unroll
        for (int ni = 0; ni < 4; ni++) acc[mi][ni] = z;
    for (int k0 = 0; k0 < K; k0 += 32) {
        __syncthreads();
        #pragma unroll
        for (int it = 0; it < 4; it++) {
            int i = tid + it * 256;
            int row = i >> 3, c0 = (i & 7) * 4;
            float4 va = *(const float4*)(A + (long long)(m0 + row) * K + k0 + c0);
            u16 h4[4], l4[4];
            splitf(va.x, h4[0], l4[0]); splitf(va.y, h4[1], l4[1]);
            splitf(va.z, h4[2], l4[2]); splitf(va.w, h4[3], l4[3]);
            *(uint2*)&sAh[row][c0] = *(uint2*)h4;
            *(uint2*)&sAl[row][c0] = *(uint2*)l4;
            float4 vb = *(const float4*)(B + (long long)(n0 + row) * K + k0 + c0);
            splitf(vb.x, h4[0], l4[0]); splitf(vb.y, h4[1], l4[1]);
            splitf(vb.z, h4[2], l4[2]); splitf(vb.w, h4[3], l4[3]);
            *(uint2*)&sBh[row][c0] = *(uint2*)h4;
            *(uint2*)&sBl[row][c0] = *(uint2*)l4;
        }
        __syncthreads();
        f16x8 ah[4], al[4];
        #pragma unroll
        for (int mi = 0; mi < 4; mi++) {
            ah[mi] = *(const f16x8*)&sAh[wrow + mi * 16 + l16][kg * 8];
            al[mi] = *(const f16x8*)&sAl[wrow + mi * 16 + l16][kg * 8];
        }
        #pragma unroll
        for (int ni = 0; ni < 4; ni++) {
            f16x8 bh = *(const f16x8*)&sBh[wcol + ni * 16 + l16][kg * 8];
            f16x8 bl = *(const f16x8*)&sBl[wcol + ni * 16 + l16][kg * 8];
            #pragma unroll
            for (int mi = 0; mi < 4; mi++) {
                acc[mi][ni] = mfma16h(ah[mi], bh, acc[mi][ni]);
                acc[mi][ni] = mfma16h(ah[mi], bl, acc[mi][ni]);
                acc[mi][ni] = mfma16h(al[mi], bh, acc[mi][ni]);
            }
        }
    }
    #pragma unroll
    for (int mi = 0; mi < 4; mi++)
        #pragma unroll
        for (int ni = 0; ni < 4; ni++)
            #pragma unroll
            for (int r = 0; r < 4; r++) {
                long long row = m0 + wrow + mi * 16 + kg * 4 + r;
                int col = ccol0 + n0 + wcol + ni * 16 + l16;
                float v = acc[mi][ni][r];
                if constexpr (EPI == 1) v += resid[row * ldc + col];
                C[row * ldc + col] = v;
            }
}

// ---------------------------------------------------------------- GEMM (NT) bf16: C = A(bf16) @ B(fp32->bf16)^T
// EPI 0: bf16 store.  EPI 2 (DUAL): silu(C1)*C2 -> bf16.
template <int BN_, int FN_, bool DUAL, int EPI, bool GROUPED>
__global__ __launch_bounds__(256, 2) void k_gemm(
    const u16* __restrict__ A, const float* __restrict__ B1g, const float* __restrict__ B2g,
    void* __restrict__ Cv, int M, int K, int ldc,
    const int* __restrict__ segoff, long long strideB) {
    constexpr int BM_ = 128, BK_ = 32, LDT = BK_ + 8;
    int tid = threadIdx.x, lane = tid & 63, wvi = tid >> 6;
    int l16 = lane & 15, kg = lane >> 4;
    int n0 = blockIdx.x * BN_;
    int m0 = blockIdx.y * BM_;
    const float* B1 = B1g;
    const float* B2 = B2g;
    int Me = M;
    long long crow0 = 0;
    if (GROUPED) {
        int e = blockIdx.z;
        int r0 = segoff[e], r1 = segoff[e + 1];
        Me = r1 - r0;
        if (m0 >= Me) return;
        A += (long long)r0 * K;
        crow0 = r0;
        B1 += (long long)e * strideB;
        if (DUAL) B2 += (long long)e * strideB;
    }
    __shared__ __align__(16) u16 sA[BM_][LDT];
    __shared__ __align__(16) u16 sB[DUAL ? 2 : 1][BN_][LDT];
    int wrow = (wvi >> 1) * 64;
    int wcol = (wvi & 1) * (BN_ / 2);
    f32x4 z = {0.f, 0.f, 0.f, 0.f};
    f32x4 acc[4][FN_];
    f32x4 acc2[DUAL ? 4 : 1][DUAL ? FN_ : 1];
    #pragma unroll
    for (int mi = 0; mi < 4; mi++)
        #pragma unroll
        for (int ni = 0; ni < FN_; ni++) {
            acc[mi][ni] = z;
            if (DUAL) acc2[mi][ni] = z;
        }
    for (int k0 = 0; k0 < K; k0 += BK_) {
        __syncthreads();
        #pragma unroll
        for (int i = tid; i < BM_ * 4; i += 256) {
            int row = i >> 2, c0 = (i & 3) * 8;
            int gr = m0 + row;
            if (GROUPED) gr = imin(gr, Me - 1);
            *(uint4*)&sA[row][c0] = *(const uint4*)(A + (long long)gr * K + k0 + c0);
        }
        #pragma unroll
        for (int i = tid; i < BN_ * 4; i += 256) {
            int row = i >> 2, c0 = (i & 3) * 8;
            const float* bp = B1 + (long long)(n0 + row) * K + k0 + c0;
            float4 f0 = *(const float4*)bp;
            float4 f1 = *(const float4*)(bp + 4);
            u16 t8[8] = { f2u(f0.x), f2u(f0.y), f2u(f0.z), f2u(f0.w),
                          f2u(f1.x), f2u(f1.y), f2u(f1.z), f2u(f1.w) };
            *(uint4*)&sB[0][row][c0] = *(uint4*)t8;
            if (DUAL) {
                const float* bp2 = B2 + (long long)(n0 + row) * K + k0 + c0;
                float4 g0 = *(const float4*)bp2;
                float4 g1 = *(const float4*)(bp2 + 4);
                u16 s8[8] = { f2u(g0.x), f2u(g0.y), f2u(g0.z), f2u(g0.w),
                              f2u(g1.x), f2u(g1.y), f2u(g1.z), f2u(g1.w) };
                *(uint4*)&sB[1][row][c0] = *(uint4*)s8;
            }
        }
        __syncthreads();
        bf16x8 af[4];
        #pragma unroll
        for (int mi = 0; mi < 4; mi++)
            af[mi] = *(const bf16x8*)&sA[wrow + mi * 16 + l16][kg * 8];
        #pragma unroll
        for (int ni = 0; ni < FN_; ni++) {
            bf16x8 bb = *(const bf16x8*)&sB[0][wcol + ni * 16 + l16][kg * 8];
            #pragma unroll
            for (int mi = 0; mi < 4; mi++) acc[mi][ni] = mfma16(af[mi], bb, acc[mi][ni]);
        }
        if (DUAL) {
            #pragma unroll
            for (int ni = 0; ni < FN_; ni++) {
                bf16x8 bb = *(const bf16x8*)&sB[1][wcol + ni * 16 + l16][kg * 8];
                #pragma unroll
                for (int mi = 0; mi < 4; mi++) acc2[mi][ni] = mfma16(af[mi], bb, acc2[mi][ni]);
            }
        }
    }
    #pragma unroll
    for (int mi = 0; mi < 4; mi++)
        #pragma unroll
        for (int ni = 0; ni < FN_; ni++)
            #pragma unroll
            for (int r = 0; r < 4; r++) {
                int rl = wrow + mi * 16 + kg * 4 + r;
                if (GROUPED && (m0 + rl >= Me)) continue;
                long long grow = crow0 + m0 + rl;
                int gcol = n0 + wcol + ni * 16 + l16;
                float v = acc[mi][ni][r];
                if constexpr (EPI == 0) {
                    ((u16*)Cv)[grow * ldc + gcol] = f2u(v);
                } else {
                    float g = v, u = acc2[mi][ni][r];
                    ((u16*)Cv)[grow * ldc + gcol] = f2u(g / (1.f + expf(-g)) * u);
                }
            }
}

// ---------------------------------------------------------------- RoPE fp32 in-place using fp64-built table
__global__ void k_rope32(float* __restrict__ qkv, const float* __restrict__ ct,
                         const float* __restrict__ st) {
    int t = blockIdx.x;
    int s = t & (Sn - 1);
    float* row = qkv + (long long)t * 3072;
    #pragma unroll
    for (int i2 = 0; i2 < 4; i2++) {
        int p = threadIdx.x + i2 * 256;  // 1024 pairs: q then k
        int part = p >> 9;
        int hp = p & 511;
        int hh = hp >> 5, j = hp & 31;
        float* base = row + part * 1024 + hh * 64 + j;
        float cs = ct[s * 32 + j], sn = st[s * 32 + j];
        float a = base[0], bb = base[32];
        base[0]  = a * cs - bb * sn;
        base[32] = bb * cs + a * sn;
    }
}

// ---------------------------------------------------------------- flash causal attention, fp32 I/O, single-f16 MFMA
// Q/K/V rounded once to f16 (2^-11 rel err; final-output contribution ~1e-3,
// far below the bf16-MoE-dominated absmax). LDS halved vs split version:
// 36.9 KB -> 4 blocks/CU. V^T staging key-index XOR-swizzled by ((dh>>2)&7)<<3
// (8-u16 granularity: preserves ds_read_b128 16B alignment; same involution on
// write and read) to break the 16-way column-write bank conflict.
__global__ __launch_bounds__(256, 4) void k_attn16(const float* __restrict__ qkv,
                                                   float* __restrict__ ctx) {
    __shared__ __align__(16) u16 Qs[64][72];
    __shared__ __align__(16) u16 Ks[64][72];
    __shared__ __align__(16) u16 Vs[64][72];     // V transposed: [dh][key], swizzled
    __shared__ __align__(16) u16 Ps[4][16][72];
    int qt = 31 - blockIdx.x;                    // heavy tiles first (causal imbalance)
    int bh = blockIdx.y;
    int b = bh >> 4, h = bh & 15;
    int q0 = qt * 64;
    int tid = threadIdx.x, lane = tid & 63, wvi = tid >> 6;
    int l16 = lane & 15, kg = lane >> 4;
    const float* qb = qkv + (long long)b * Sn * 3072 + h * 64;
    const float* kb = qb + 1024;
    const float* vb = qb + 2048;
    #pragma unroll
    for (int it = 0; it < 4; it++) {
        int i = tid + it * 256;
        int r = i >> 4, c0 = (i & 15) * 4;
        float4 v = *(const float4*)(qb + (long long)(q0 + r) * 3072 + c0);
        u16 h4[4] = { f2h(v.x), f2h(v.y), f2h(v.z), f2h(v.w) };
        *(uint2*)&Qs[r][c0] = *(uint2*)h4;
    }
    float ms[4], ls[4];
    f32x4 oa[4];
    f32x4 z = {0.f, 0.f, 0.f, 0.f};
    #pragma unroll
    for (int r = 0; r < 4; r++) { ms[r] = -1e30f; ls[r] = 0.f; }
    #pragma unroll
    for (int nf = 0; nf < 4; nf++) oa[nf] = z;
    int nkt = qt + 1;
    for (int kt = 0; kt < nkt; kt++) {
        int k0 = kt * 64;
        __syncthreads();
        #pragma unroll
        for (int it = 0; it < 4; it++) {
            int i = tid + it * 256;
            int r = i >> 4, c0 = (i & 15) * 4;
            float4 v = *(const float4*)(kb + (long long)(k0 + r) * 3072 + c0);
            u16 h4[4] = { f2h(v.x), f2h(v.y), f2h(v.z), f2h(v.w) };
            *(uint2*)&Ks[r][c0] = *(uint2*)h4;
            float4 w = *(const float4*)(vb + (long long)(k0 + r) * 3072 + c0);
            int rs = r ^ (((c0 >> 2) & 7) << 3);  // (c0+j)>>2 == c0>>2 for j<4
            Vs[c0 + 0][rs] = f2h(w.x);
            Vs[c0 + 1][rs] = f2h(w.y);
            Vs[c0 + 2][rs] = f2h(w.z);
            Vs[c0 + 3][rs] = f2h(w.w);
        }
        __syncthreads();
        // S = Q K^T (single f16)
        f32x4 sf[4];
        #pragma unroll
        for (int ni = 0; ni < 4; ni++) sf[ni] = z;
        __builtin_amdgcn_s_setprio(1);
        #pragma unroll
        for (int kk = 0; kk < 2; kk++) {
            f16x8 aq = *(const f16x8*)&Qs[wvi * 16 + l16][kk * 32 + kg * 8];
            #pragma unroll
            for (int ni = 0; ni < 4; ni++) {
                f16x8 bk = *(const f16x8*)&Ks[ni * 16 + l16][kk * 32 + kg * 8];
                sf[ni] = mfma16h(aq, bk, sf[ni]);
            }
        }
        __builtin_amdgcn_s_setprio(0);
        // online softmax (fp32); rows of this wave: kg*4+r
        #pragma unroll
        for (int r = 0; r < 4; r++) {
            int qg = q0 + wvi * 16 + kg * 4 + r;
            float mx = -1e30f;
            #pragma unroll
            for (int ni = 0; ni < 4; ni++) {
                float v = sf[ni][r] * 0.125f;
                if (k0 + ni * 16 + l16 > qg) v = -1e30f;
                sf[ni][r] = v;
                mx = fmaxf(mx, v);
            }
            mx = fmaxf(mx, __shfl_xor(mx, 1)); mx = fmaxf(mx, __shfl_xor(mx, 2));
            mx = fmaxf(mx, __shfl_xor(mx, 4)); mx = fmaxf(mx, __shfl_xor(mx, 8));
            float mnew = fmaxf(ms[r], mx);
            float alpha = expf(ms[r] - mnew);
            float rs = 0.f;
            #pragma unroll
            for (int ni = 0; ni < 4; ni++) {
                float p = (k0 + ni * 16 + l16 > qg) ? 0.f : expf(sf[ni][r] - mnew);
                Ps[wvi][kg * 4 + r][ni * 16 + l16] = f2h(p);
                rs += p;
            }
            rs += __shfl_xor(rs, 1); rs += __shfl_xor(rs, 2);
            rs += __shfl_xor(rs, 4); rs += __shfl_xor(rs, 8);
            ls[r] = ls[r] * alpha + rs;
            ms[r] = mnew;
            #pragma unroll
            for (int nf = 0; nf < 4; nf++) oa[nf][r] *= alpha;
        }
        // O += P V (single f16), P read back in A-layout (wave-private LDS)
        __builtin_amdgcn_s_setprio(1);
        #pragma unroll
        for (int kk = 0; kk < 2; kk++) {
            f16x8 pa = *(const f16x8*)&Ps[wvi][l16][kk * 32 + kg * 8];
            #pragma unroll
            for (int nf = 0; nf < 4; nf++) {
                int vrow = nf * 16 + l16;
                f16x8 vv = *(const f16x8*)&Vs[vrow][(kk * 32 + kg * 8) ^ (((vrow >> 2) & 7) << 3)];
                oa[nf] = mfma16h(pa, vv, oa[nf]);
            }
        }
        __builtin_amdgcn_s_setprio(0);
    }
    #pragma unroll
    for (int r = 0; r < 4; r++) {
        float inv = 1.f / ls[r];
        int qg = q0 + wvi * 16 + kg * 4 + r;
        long long orow = (long long)(b * Sn + qg) * Dn + h * 64;
        #pragma unroll
        for (int nf = 0; nf < 4; nf++)
            ctx[orow + nf * 16 + l16] = oa[nf][r] * inv;
    }
}

// ---------------------------------------------------------------- router: fp64-accum logits, top-2, atomic slot assign
__global__ void k_router(const float* __restrict__ x2, const float* __restrict__ w2,
                         const float* __restrict__ rw, const float* __restrict__ bias,
                         int* __restrict__ cnt, int* __restrict__ te,
                         int* __restrict__ tpos, float* __restrict__ tw) {
    int wvi = threadIdx.x >> 6, lane = threadIdx.x & 63;
    int t = blockIdx.x * 4 + wvi;
    const float* xr = x2 + (long long)t * Dn;
    float xn[16];
    float ss = 0.f;
    #pragma unroll
    for (int j = 0; j < 16; j++) {
        float v = xr[lane + j * 64];
        ss += v * v;
        xn[j] = v * w2[lane + j * 64];
    }
    ss += __shfl_xor(ss, 1);  ss += __shfl_xor(ss, 2);  ss += __shfl_xor(ss, 4);
    ss += __shfl_xor(ss, 8);  ss += __shfl_xor(ss, 16); ss += __shfl_xor(ss, 32);
    float sc = rsqrtf(ss * (1.f / Dn) + 1e-6f);
    double lg[En];
    for (int e = 0; e < En; e++) {
        const float* rwe = rw + e * Dn;
        double a = 0.0;
        #pragma unroll
        for (int j = 0; j < 16; j++) a += (double)xn[j] * (double)rwe[lane + j * 64];
        a += __shfl_xor(a, 1);  a += __shfl_xor(a, 2);  a += __shfl_xor(a, 4);
        a += __shfl_xor(a, 8);  a += __shfl_xor(a, 16); a += __shfl_xor(a, 32);
        lg[e] = a;
    }
    if (lane == 0) {
        double g[En];
        for (int e = 0; e < En; e++)
            g[e] = 1.0 / (1.0 + exp(-((double)sc * lg[e] + (double)bias[e])));
        int e0 = 0; double b0 = g[0];
        for (int e = 1; e < En; e++) if (g[e] > b0) { b0 = g[e]; e0 = e; }
        int e1 = -1; double b1 = -1.0;
        for (int e = 0; e < En; e++) if (e != e0 && g[e] > b1) { b1 = g[e]; e1 = e; }
        double sum = b0 + b1 + 1e-9;
        int p0 = atomicAdd(&cnt[e0], 1);
        int p1 = atomicAdd(&cnt[e1], 1);
        te[2 * t] = e0;       te[2 * t + 1] = e1;
        tpos[2 * t] = p0;     tpos[2 * t + 1] = p1;
        tw[2 * t] = (float)(b0 / sum);
        tw[2 * t + 1] = (float)(b1 / sum);
    }
}

// ---------------------------------------------------------------- scan 16 counts
__global__ void k_scan(const int* __restrict__ cnt, int* __restrict__ offs) {
    if (threadIdx.x == 0) {
        int a = 0;
        for (int e = 0; e < En; e++) { offs[e] = a; a += cnt[e]; }
        offs[En] = a;
    }
}

// ---------------------------------------------------------------- gather h2 rows into expert-sorted xg
__global__ void k_gather(const u16* __restrict__ h2, u16* __restrict__ xg,
                         const int* __restrict__ te, const int* __restrict__ tpos,
                         const int* __restrict__ offs) {
    int p = blockIdx.x;
    int t = p >> 1;
    int slot = offs[te[p]] + tpos[p];
    const uint4* src = (const uint4*)(h2 + (long long)t * Dn);
    uint4* dst = (uint4*)(xg + (long long)slot * Dn);
    dst[threadIdx.x] = src[threadIdx.x];
}

// ---------------------------------------------------------------- combine: out = x2 + shared + w0*d0 + w1*d1
__global__ void k_combine(const float* __restrict__ x2, const u16* __restrict__ sho,
                          const u16* __restrict__ dwn, const int* __restrict__ te,
                          const int* __restrict__ tpos, const int* __restrict__ offs,
                          const float* __restrict__ tw, float* __restrict__ out) {
    int t = blockIdx.x;
    int s0 = offs[te[2 * t]] + tpos[2 * t];
    int s1 = offs[te[2 * t + 1]] + tpos[2 * t + 1];
    float w0 = tw[2 * t], w1 = tw[2 * t + 1];
    int i = threadIdx.x;
    float4 xv = ((const float4*)(x2 + (long long)t * Dn))[i];
    uint2 shv = ((const uint2*)(sho + (long long)t * Dn))[i];
    uint2 dv0 = ((const uint2*)(dwn + (long long)s0 * Dn))[i];
    uint2 dv1 = ((const uint2*)(dwn + (long long)s1 * Dn))[i];
    u16 s4[4], a4[4], b4[4];
    *(uint2*)s4 = shv; *(uint2*)a4 = dv0; *(uint2*)b4 = dv1;
    float4 o;
    o.x = xv.x + u2f(s4[0]) + w0 * u2f(a4[0]) + w1 * u2f(b4[0]);
    o.y = xv.y + u2f(s4[1]) + w0 * u2f(a4[1]) + w1 * u2f(b4[1]);
    o.z = xv.z + u2f(s4[2]) + w0 * u2f(a4[2]) + w1 * u2f(b4[2]);
    o.w = xv.w + u2f(s4[3]) + w0 * u2f(a4[3]) + w1 * u2f(b4[3]);
    ((float4*)(out + (long long)t * Dn))[i] = o;
}

// ---------------------------------------------------------------- launch
extern "C" void kernel_launch(void* const* d_in, const int* in_sizes, int n_in,
                              void* d_out, int out_size, void* d_ws, size_t ws_size,
                              hipStream_t stream) {
    const float* x     = (const float*)d_in[0];
    const float* n1w   = (const float*)d_in[1];
    const float* wq    = (const float*)d_in[2];
    const float* wk    = (const float*)d_in[3];
    const float* wvp   = (const float*)d_in[4];
    const float* wo    = (const float*)d_in[5];
    const float* n2w   = (const float*)d_in[6];
    const float* rw    = (const float*)d_in[7];
    const float* ebias = (const float*)d_in[8];
    const float* sg    = (const float*)d_in[9];
    const float* su    = (const float*)d_in[10];
    const float* sd    = (const float*)d_in[11];
    const float* eg    = (const float*)d_in[12];
    const float* eu    = (const float*)d_in[13];
    const float* ed    = (const float*)d_in[14];

    char* ws = (char*)d_ws;
    // layout (bytes):
    //   [0,32M)      h1 fp32     -> ctx fp32 (alias) -> sho bf16 [0,16M)
    //   [16M,48M)    dwn bf16 (written after ctx/xg dead)
    //   [32M,128M)   qkv fp32    -> xg bf16 [32M,64M) after attention
    //   [64M,80M)    acts bf16 (shared expert activations)
    //   [80M,112M)   actr bf16 (routed activations)
    //   [128M,160M)  x2 fp32
    //   [160M,176M)  h2 bf16
    //   [176M,...)   meta + rope tables
    float* h1   = (float*)(ws + 0);
    u16*   sho  = (u16*)(ws + 0);
    u16*   dwn  = (u16*)(ws + 16777216);
    float* qkv  = (float*)(ws + 33554432);
    u16*   xg   = (u16*)(ws + 33554432);
    u16*   acts = (u16*)(ws + 67108864);
    u16*   actr = (u16*)(ws + 83886080);
    float* x2   = (float*)(ws + 134217728);
    u16*   h2   = (u16*)(ws + 167772160);
    char*  meta = ws + 184549376;
    int*   cnt  = (int*)(meta);
    int*   offs = (int*)(meta + 256);
    int*   te   = (int*)(meta + 512);
    int*   tpos = (int*)(meta + 512 + 65536);
    float* tw   = (float*)(meta + 512 + 131072);
    float* ct   = (float*)(meta + 262144);
    float* st   = (float*)(meta + 524288);
    float* ctx  = h1;
    float* out  = (float*)d_out;

    k_zero<<<1, 64, 0, stream>>>(cnt);
    k_ropetab<<<256, 256, 0, stream>>>(ct, st);
    k_rmsnorm<false><<<Tn, 256, 0, stream>>>(x, n1w, h1);
    dim3 g32(8, 64, 1);
    k_gemm32<0><<<g32, 256, 0, stream>>>(h1, wq,  qkv, nullptr, Dn, 3072, 0);
    k_gemm32<0><<<g32, 256, 0, stream>>>(h1, wk,  qkv, nullptr, Dn, 3072, 1024);
    k_gemm32<0><<<g32, 256, 0, stream>>>(h1, wvp, qkv, nullptr, Dn, 3072, 2048);
    k_rope32<<<Tn, 256, 0, stream>>>(qkv, ct, st);
    k_attn16<<<dim3(32, 64), 256, 0, stream>>>(qkv, ctx);
    k_gemm32<1><<<g32, 256, 0, stream>>>(ctx, wo, x2, x, Dn, 1024, 0);
    k_rmsnorm<true><<<Tn, 256, 0, stream>>>(x2, n2w, h2);
    k_router<<<Tn / 4, 256, 0, stream>>>(x2, n2w, rw, ebias, cnt, te, tpos, tw);
    k_scan<<<1, 64, 0, stream>>>(cnt, offs);
    k_gather<<<Tn * 2, 128, 0, stream>>>(h2, xg, te, tpos, offs);
    // shared expert: gate+up fused, then down (bf16)
    k_gemm<64, 2, true, 2, false><<<dim3(16, 64, 1), 256, 0, stream>>>(h2, sg, su, acts, Tn, Dn, In, nullptr, 0);
    k_gemm<128, 4, false, 0, false><<<dim3(8, 64, 1), 256, 0, stream>>>(acts, sd, nullptr, sho, Tn, In, Dn, nullptr, 0);
    // routed experts: grouped gate+up fused, grouped down (bf16)
    k_gemm<64, 2, true, 2, true><<<dim3(16, 64, En), 256, 0, stream>>>(xg, eg, eu, actr, 0, Dn, In, offs, (long long)In * Dn);
    k_gemm<128, 4, false, 0, true><<<dim3(8, 64, En), 256, 0, stream>>>(actr, ed, nullptr, dwn, 0, In, Dn, offs, (long long)Dn * In);
    k_combine<<<Tn, 256, 0, stream>>>(x2, sho, dwn, te, tpos, offs, tw, out);
}

// Round 3
// 1390.211 us; speedup vs baseline: 1.5376x; 1.2772x over previous
//
#include <hip/hip_runtime.h>
#include <hip/hip_bf16.h>
#include <stdint.h>

#define Bn 4
#define Sn 2048
#define Dn 1024
#define Hn 16
#define DHn 64
#define En 16
#define In 1024
#define Tn 8192   // B*S

typedef float f32x4 __attribute__((ext_vector_type(4)));
typedef __bf16 bf16x8 __attribute__((ext_vector_type(8)));
typedef _Float16 f16;
typedef _Float16 f16x8 __attribute__((ext_vector_type(8)));
typedef unsigned short u16;
typedef unsigned int u32;

__device__ __forceinline__ u16 f2u(float f) {
    __bf16 h = (__bf16)f;
    return __builtin_bit_cast(u16, h);
}
__device__ __forceinline__ float u2f(u16 u) {
    return (float)__builtin_bit_cast(__bf16, u);
}
__device__ __forceinline__ u16 f2h(float f) {
    f16 h = (f16)f;
    return __builtin_bit_cast(u16, h);
}
__device__ __forceinline__ f32x4 mfma16(bf16x8 a, bf16x8 b, f32x4 c) {
    return __builtin_amdgcn_mfma_f32_16x16x32_bf16(a, b, c, 0, 0, 0);
}
__device__ __forceinline__ f32x4 mfma16h(f16x8 a, f16x8 b, f32x4 c) {
    return __builtin_amdgcn_mfma_f32_16x16x32_f16(a, b, c, 0, 0, 0);
}
__device__ __forceinline__ void splitf(float f, u16& h, u16& l) {
    f16 hh = (f16)f;
    f16 ll = (f16)(f - (float)hh);
    h = __builtin_bit_cast(u16, hh);
    l = __builtin_bit_cast(u16, ll);
}
__device__ __forceinline__ int imin(int a, int b) { return a < b ? a : b; }

// ---------------------------------------------------------------- zero meta
__global__ void k_zero(int* cnt) {
    if (threadIdx.x < En) cnt[threadIdx.x] = 0;
}

// ---------------------------------------------------------------- fp64 RoPE table: cos/sin [S][32]
__global__ void k_ropetab(float* __restrict__ ct, float* __restrict__ st) {
    int i = blockIdx.x * 256 + threadIdx.x;  // 65536 entries
    int s = i >> 5, j = i & 31;
    double inv = pow(10000.0, -(double)j / 32.0);
    double ang = (double)s * inv;
    ct[i] = (float)cos(ang);
    st[i] = (float)sin(ang);
}

// ---------------------------------------------------------------- rmsnorm: fp32 in -> bf16 (MODE 1) or split-f16 pair (MODE 2)
template <int MODE>
__global__ void k_rmsnorm(const float* __restrict__ x, const float* __restrict__ w,
                          void* __restrict__ outv, void* __restrict__ outv2) {
    int t = blockIdx.x;
    const float4* xr = (const float4*)(x + (long long)t * Dn);
    float4 v = xr[threadIdx.x];
    float ss = v.x * v.x + v.y * v.y + v.z * v.z + v.w * v.w;
    ss += __shfl_xor(ss, 1);  ss += __shfl_xor(ss, 2);  ss += __shfl_xor(ss, 4);
    ss += __shfl_xor(ss, 8);  ss += __shfl_xor(ss, 16); ss += __shfl_xor(ss, 32);
    __shared__ float sred[4];
    int lane = threadIdx.x & 63, wvi = threadIdx.x >> 6;
    if (lane == 0) sred[wvi] = ss;
    __syncthreads();
    float tot = sred[0] + sred[1] + sred[2] + sred[3];
    float sc = rsqrtf(tot * (1.f / Dn) + 1e-6f);
    const float4* wr = (const float4*)w;
    float4 w4 = wr[threadIdx.x];
    if constexpr (MODE == 1) {
        u16 o4[4] = { f2u(v.x * sc * w4.x), f2u(v.y * sc * w4.y),
                      f2u(v.z * sc * w4.z), f2u(v.w * sc * w4.w) };
        ((uint2*)((u16*)outv + (long long)t * Dn))[threadIdx.x] = *(uint2*)o4;
    } else {
        u16 h4[4], l4[4];
        splitf(v.x * sc * w4.x, h4[0], l4[0]);
        splitf(v.y * sc * w4.y, h4[1], l4[1]);
        splitf(v.z * sc * w4.z, h4[2], l4[2]);
        splitf(v.w * sc * w4.w, h4[3], l4[3]);
        ((uint2*)((u16*)outv  + (long long)t * Dn))[threadIdx.x] = *(uint2*)h4;
        ((uint2*)((u16*)outv2 + (long long)t * Dn))[threadIdx.x] = *(uint2*)l4;
    }
}

// ---------------------------------------------------------------- split 4 [1024x1024] fp32 weight mats into f16 hi/lo (once)
__global__ void k_splitw4(const float* __restrict__ w0, const float* __restrict__ w1,
                          const float* __restrict__ w2, const float* __restrict__ w3,
                          u16* __restrict__ oh, u16* __restrict__ ol) {
    int m = blockIdx.y;
    const float* w = (m == 0) ? w0 : (m == 1) ? w1 : (m == 2) ? w2 : w3;
    long long i = ((long long)blockIdx.x * 256 + threadIdx.x) * 4;
    float4 v = *(const float4*)(w + i);
    u16 h4[4], l4[4];
    splitf(v.x, h4[0], l4[0]); splitf(v.y, h4[1], l4[1]);
    splitf(v.z, h4[2], l4[2]); splitf(v.w, h4[3], l4[3]);
    long long o = (long long)m * 1048576 + i;
    *(uint2*)(oh + o) = *(uint2*)h4;
    *(uint2*)(ol + o) = *(uint2*)l4;
}

// ---------------------------------------------------------------- fp32-accurate GEMM from pre-split f16 hi/lo (NT), 3-term MFMA
// EPI 0: RoPE + f16(u16) store (Q/K).  EPI 1: f16(u16) store (V).
// EPI 2: fp32 store + residual add (wo).
template <int EPI>
__global__ __launch_bounds__(256, 3) void k_gemm32s(
    const u16* __restrict__ Ah, const u16* __restrict__ Al,
    const u16* __restrict__ Bh, const u16* __restrict__ Bl,
    void* __restrict__ Cv, const float* __restrict__ resid,
    const float* __restrict__ ct, const float* __restrict__ st,
    int K, int ldc, int ccol0) {
    constexpr int LDT = 40;
    __shared__ __align__(16) u16 sAh[128][LDT], sAl[128][LDT];
    __shared__ __align__(16) u16 sBh[128][LDT], sBl[128][LDT];
    int tid = threadIdx.x, lane = tid & 63, wvi = tid >> 6;
    int l16 = lane & 15, kg = lane >> 4;
    int n0 = blockIdx.x * 128, m0 = blockIdx.y * 128;
    int wrow = (wvi >> 1) * 64, wcol = (wvi & 1) * 64;
    f32x4 z = {0.f, 0.f, 0.f, 0.f};
    f32x4 acc[4][4];
    #pragma unroll
    for (int mi = 0; mi < 4; mi++)
        #pragma unroll
        for (int ni = 0; ni < 4; ni++) acc[mi][ni] = z;
    for (int k0 = 0; k0 < K; k0 += 32) {
        __syncthreads();
        #pragma unroll
        for (int it = 0; it < 2; it++) {
            int i = tid + it * 256;           // 0..511
            int row = i >> 2, c0 = (i & 3) * 8;
            long long ga = (long long)(m0 + row) * K + k0 + c0;
            long long gb = (long long)(n0 + row) * K + k0 + c0;
            *(uint4*)&sAh[row][c0] = *(const uint4*)(Ah + ga);
            *(uint4*)&sAl[row][c0] = *(const uint4*)(Al + ga);
            *(uint4*)&sBh[row][c0] = *(const uint4*)(Bh + gb);
            *(uint4*)&sBl[row][c0] = *(const uint4*)(Bl + gb);
        }
        __syncthreads();
        f16x8 ah[4], al[4];
        #pragma unroll
        for (int mi = 0; mi < 4; mi++) {
            ah[mi] = *(const f16x8*)&sAh[wrow + mi * 16 + l16][kg * 8];
            al[mi] = *(const f16x8*)&sAl[wrow + mi * 16 + l16][kg * 8];
        }
        #pragma unroll
        for (int ni = 0; ni < 4; ni++) {
            f16x8 bh = *(const f16x8*)&sBh[wcol + ni * 16 + l16][kg * 8];
            f16x8 bl = *(const f16x8*)&sBl[wcol + ni * 16 + l16][kg * 8];
            #pragma unroll
            for (int mi = 0; mi < 4; mi++) {
                acc[mi][ni] = mfma16h(ah[mi], bh, acc[mi][ni]);
                acc[mi][ni] = mfma16h(ah[mi], bl, acc[mi][ni]);
                acc[mi][ni] = mfma16h(al[mi], bh, acc[mi][ni]);
            }
        }
    }
    if constexpr (EPI == 0) {
        // RoPE fused: partner (j, j+32) is (ni, ni+2) of the same thread
        u16* C = (u16*)Cv;
        #pragma unroll
        for (int mi = 0; mi < 4; mi++)
            #pragma unroll
            for (int r = 0; r < 4; r++) {
                long long row = m0 + wrow + mi * 16 + kg * 4 + r;
                int s = (int)(row & (Sn - 1));
                #pragma unroll
                for (int ni = 0; ni < 2; ni++) {
                    int j = ni * 16 + l16;
                    float cs = ct[s * 32 + j], sn = st[s * 32 + j];
                    float a = acc[mi][ni][r], b2 = acc[mi][ni + 2][r];
                    int col = ccol0 + n0 + wcol + ni * 16 + l16;
                    C[row * ldc + col]      = f2h(a * cs - b2 * sn);
                    C[row * ldc + col + 32] = f2h(b2 * cs + a * sn);
                }
            }
    } else if constexpr (EPI == 1) {
        u16* C = (u16*)Cv;
        #pragma unroll
        for (int mi = 0; mi < 4; mi++)
            #pragma unroll
            for (int ni = 0; ni < 4; ni++)
                #pragma unroll
                for (int r = 0; r < 4; r++) {
                    long long row = m0 + wrow + mi * 16 + kg * 4 + r;
                    int col = ccol0 + n0 + wcol + ni * 16 + l16;
                    C[row * ldc + col] = f2h(acc[mi][ni][r]);
                }
    } else {
        float* C = (float*)Cv;
        #pragma unroll
        for (int mi = 0; mi < 4; mi++)
            #pragma unroll
            for (int ni = 0; ni < 4; ni++)
                #pragma unroll
                for (int r = 0; r < 4; r++) {
                    long long row = m0 + wrow + mi * 16 + kg * 4 + r;
                    int col = ccol0 + n0 + wcol + ni * 16 + l16;
                    C[row * ldc + col] = acc[mi][ni][r] + resid[row * ldc + col];
                }
    }
}

// ---------------------------------------------------------------- GEMM (NT) bf16: C = A(bf16) @ B(fp32->bf16)^T
// EPI 0: bf16 store.  EPI 2 (DUAL): silu(C1)*C2 -> bf16.
template <int BN_, int FN_, bool DUAL, int EPI, bool GROUPED>
__global__ __launch_bounds__(256, 2) void k_gemm(
    const u16* __restrict__ A, const float* __restrict__ B1g, const float* __restrict__ B2g,
    void* __restrict__ Cv, int M, int K, int ldc,
    const int* __restrict__ segoff, long long strideB) {
    constexpr int BM_ = 128, BK_ = 32, LDT = BK_ + 8;
    int tid = threadIdx.x, lane = tid & 63, wvi = tid >> 6;
    int l16 = lane & 15, kg = lane >> 4;
    int n0 = blockIdx.x * BN_;
    int m0 = blockIdx.y * BM_;
    const float* B1 = B1g;
    const float* B2 = B2g;
    int Me = M;
    long long crow0 = 0;
    if (GROUPED) {
        int e = blockIdx.z;
        int r0 = segoff[e], r1 = segoff[e + 1];
        Me = r1 - r0;
        if (m0 >= Me) return;
        A += (long long)r0 * K;
        crow0 = r0;
        B1 += (long long)e * strideB;
        if (DUAL) B2 += (long long)e * strideB;
    }
    __shared__ __align__(16) u16 sA[BM_][LDT];
    __shared__ __align__(16) u16 sB[DUAL ? 2 : 1][BN_][LDT];
    int wrow = (wvi >> 1) * 64;
    int wcol = (wvi & 1) * (BN_ / 2);
    f32x4 z = {0.f, 0.f, 0.f, 0.f};
    f32x4 acc[4][FN_];
    f32x4 acc2[DUAL ? 4 : 1][DUAL ? FN_ : 1];
    #pragma unroll
    for (int mi = 0; mi < 4; mi++)
        #pragma unroll
        for (int ni = 0; ni < FN_; ni++) {
            acc[mi][ni] = z;
            if (DUAL) acc2[mi][ni] = z;
        }
    for (int k0 = 0; k0 < K; k0 += BK_) {
        __syncthreads();
        #pragma unroll
        for (int i = tid; i < BM_ * 4; i += 256) {
            int row = i >> 2, c0 = (i & 3) * 8;
            int gr = m0 + row;
            if (GROUPED) gr = imin(gr, Me - 1);
            *(uint4*)&sA[row][c0] = *(const uint4*)(A + (long long)gr * K + k0 + c0);
        }
        #pragma unroll
        for (int i = tid; i < BN_ * 4; i += 256) {
            int row = i >> 2, c0 = (i & 3) * 8;
            const float* bp = B1 + (long long)(n0 + row) * K + k0 + c0;
            float4 f0 = *(const float4*)bp;
            float4 f1 = *(const float4*)(bp + 4);
            u16 t8[8] = { f2u(f0.x), f2u(f0.y), f2u(f0.z), f2u(f0.w),
                          f2u(f1.x), f2u(f1.y), f2u(f1.z), f2u(f1.w) };
            *(uint4*)&sB[0][row][c0] = *(uint4*)t8;
            if (DUAL) {
                const float* bp2 = B2 + (long long)(n0 + row) * K + k0 + c0;
                float4 g0 = *(const float4*)bp2;
                float4 g1 = *(const float4*)(bp2 + 4);
                u16 s8[8] = { f2u(g0.x), f2u(g0.y), f2u(g0.z), f2u(g0.w),
                              f2u(g1.x), f2u(g1.y), f2u(g1.z), f2u(g1.w) };
                *(uint4*)&sB[1][row][c0] = *(uint4*)s8;
            }
        }
        __syncthreads();
        bf16x8 af[4];
        #pragma unroll
        for (int mi = 0; mi < 4; mi++)
            af[mi] = *(const bf16x8*)&sA[wrow + mi * 16 + l16][kg * 8];
        #pragma unroll
        for (int ni = 0; ni < FN_; ni++) {
            bf16x8 bb = *(const bf16x8*)&sB[0][wcol + ni * 16 + l16][kg * 8];
            #pragma unroll
            for (int mi = 0; mi < 4; mi++) acc[mi][ni] = mfma16(af[mi], bb, acc[mi][ni]);
        }
        if (DUAL) {
            #pragma unroll
            for (int ni = 0; ni < FN_; ni++) {
                bf16x8 bb = *(const bf16x8*)&sB[1][wcol + ni * 16 + l16][kg * 8];
                #pragma unroll
                for (int mi = 0; mi < 4; mi++) acc2[mi][ni] = mfma16(af[mi], bb, acc2[mi][ni]);
            }
        }
    }
    #pragma unroll
    for (int mi = 0; mi < 4; mi++)
        #pragma unroll
        for (int ni = 0; ni < FN_; ni++)
            #pragma unroll
            for (int r = 0; r < 4; r++) {
                int rl = wrow + mi * 16 + kg * 4 + r;
                if (GROUPED && (m0 + rl >= Me)) continue;
                long long grow = crow0 + m0 + rl;
                int gcol = n0 + wcol + ni * 16 + l16;
                float v = acc[mi][ni][r];
                if constexpr (EPI == 0) {
                    ((u16*)Cv)[grow * ldc + gcol] = f2u(v);
                } else {
                    float g = v, u = acc2[mi][ni][r];
                    ((u16*)Cv)[grow * ldc + gcol] = f2u(g / (1.f + __expf(-g)) * u);
                }
            }
}

// ---------------------------------------------------------------- flash causal attention, f16(u16) QKV in, split-f16 ctx out
// Staging is pure copies (QKV already f16 from GEMM epilogue). Diagonal tile
// is the only one needing causal compares; masked lanes use exp(-1e30)->0.
// V^T staging key-index XOR-swizzled by ((dh>>2)&7)<<3 (same involution on
// write and read) to break the 16-way column-write bank conflict.
__global__ __launch_bounds__(256, 4) void k_attn16(const u16* __restrict__ qkv,
                                                   u16* __restrict__ ctxh,
                                                   u16* __restrict__ ctxl) {
    __shared__ __align__(16) u16 Qs[64][72];
    __shared__ __align__(16) u16 Ks[64][72];
    __shared__ __align__(16) u16 Vs[64][72];     // V transposed: [dh][key], swizzled
    __shared__ __align__(16) u16 Ps[4][16][72];
    int qt = 31 - blockIdx.x;                    // heavy tiles first (causal imbalance)
    int bh = blockIdx.y;
    int b = bh >> 4, h = bh & 15;
    int q0 = qt * 64;
    int tid = threadIdx.x, lane = tid & 63, wvi = tid >> 6;
    int l16 = lane & 15, kg = lane >> 4;
    const u16* qb = qkv + (long long)b * Sn * 3072 + h * 64;
    const u16* kb = qb + 1024;
    const u16* vb = qb + 2048;
    #pragma unroll
    for (int it = 0; it < 4; it++) {
        int i = tid + it * 256;
        int r = i >> 4, c0 = (i & 15) * 4;
        *(uint2*)&Qs[r][c0] = *(const uint2*)(qb + (long long)(q0 + r) * 3072 + c0);
    }
    float ms[4], ls[4];
    f32x4 oa[4];
    f32x4 z = {0.f, 0.f, 0.f, 0.f};
    #pragma unroll
    for (int r = 0; r < 4; r++) { ms[r] = -1e30f; ls[r] = 0.f; }
    #pragma unroll
    for (int nf = 0; nf < 4; nf++) oa[nf] = z;
    int nkt = qt + 1;
    for (int kt = 0; kt < nkt; kt++) {
        int k0 = kt * 64;
        __syncthreads();
        #pragma unroll
        for (int it = 0; it < 4; it++) {
            int i = tid + it * 256;
            int r = i >> 4, c0 = (i & 15) * 4;
            *(uint2*)&Ks[r][c0] = *(const uint2*)(kb + (long long)(k0 + r) * 3072 + c0);
            uint2 vw = *(const uint2*)(vb + (long long)(k0 + r) * 3072 + c0);
            u16 w4[4]; *(uint2*)w4 = vw;
            int rs = r ^ (((c0 >> 2) & 7) << 3);  // (c0+j)>>2 == c0>>2 for j<4
            Vs[c0 + 0][rs] = w4[0];
            Vs[c0 + 1][rs] = w4[1];
            Vs[c0 + 2][rs] = w4[2];
            Vs[c0 + 3][rs] = w4[3];
        }
        __syncthreads();
        // S = Q K^T
        f32x4 sf[4];
        #pragma unroll
        for (int ni = 0; ni < 4; ni++) sf[ni] = z;
        __builtin_amdgcn_s_setprio(1);
        #pragma unroll
        for (int kk = 0; kk < 2; kk++) {
            f16x8 aq = *(const f16x8*)&Qs[wvi * 16 + l16][kk * 32 + kg * 8];
            #pragma unroll
            for (int ni = 0; ni < 4; ni++) {
                f16x8 bk = *(const f16x8*)&Ks[ni * 16 + l16][kk * 32 + kg * 8];
                sf[ni] = mfma16h(aq, bk, sf[ni]);
            }
        }
        __builtin_amdgcn_s_setprio(0);
        // online softmax (fp32); rows of this wave: kg*4+r
        bool diag = (kt == qt);
        #pragma unroll
        for (int r = 0; r < 4; r++) {
            float mx = -1e30f;
            if (diag) {
                int qg = q0 + wvi * 16 + kg * 4 + r;
                #pragma unroll
                for (int ni = 0; ni < 4; ni++) {
                    float v = sf[ni][r] * 0.125f;
                    if (k0 + ni * 16 + l16 > qg) v = -1e30f;
                    sf[ni][r] = v;
                    mx = fmaxf(mx, v);
                }
            } else {
                #pragma unroll
                for (int ni = 0; ni < 4; ni++) {
                    float v = sf[ni][r] * 0.125f;
                    sf[ni][r] = v;
                    mx = fmaxf(mx, v);
                }
            }
            mx = fmaxf(mx, __shfl_xor(mx, 1)); mx = fmaxf(mx, __shfl_xor(mx, 2));
            mx = fmaxf(mx, __shfl_xor(mx, 4)); mx = fmaxf(mx, __shfl_xor(mx, 8));
            float mnew = fmaxf(ms[r], mx);
            float alpha = __expf(ms[r] - mnew);
            float rs = 0.f;
            #pragma unroll
            for (int ni = 0; ni < 4; ni++) {
                float p = __expf(sf[ni][r] - mnew);   // masked: exp(-1e30)=0
                Ps[wvi][kg * 4 + r][ni * 16 + l16] = f2h(p);
                rs += p;
            }
            rs += __shfl_xor(rs, 1); rs += __shfl_xor(rs, 2);
            rs += __shfl_xor(rs, 4); rs += __shfl_xor(rs, 8);
            ls[r] = ls[r] * alpha + rs;
            ms[r] = mnew;
            #pragma unroll
            for (int nf = 0; nf < 4; nf++) oa[nf][r] *= alpha;
        }
        // O += P V, P read back in A-layout (wave-private LDS)
        __builtin_amdgcn_s_setprio(1);
        #pragma unroll
        for (int kk = 0; kk < 2; kk++) {
            f16x8 pa = *(const f16x8*)&Ps[wvi][l16][kk * 32 + kg * 8];
            #pragma unroll
            for (int nf = 0; nf < 4; nf++) {
                int vrow = nf * 16 + l16;
                f16x8 vv = *(const f16x8*)&Vs[vrow][(kk * 32 + kg * 8) ^ (((vrow >> 2) & 7) << 3)];
                oa[nf] = mfma16h(pa, vv, oa[nf]);
            }
        }
        __builtin_amdgcn_s_setprio(0);
    }
    #pragma unroll
    for (int r = 0; r < 4; r++) {
        float inv = 1.f / ls[r];
        int qg = q0 + wvi * 16 + kg * 4 + r;
        long long orow = (long long)(b * Sn + qg) * Dn + h * 64;
        #pragma unroll
        for (int nf = 0; nf < 4; nf++) {
            u16 hh, ll;
            splitf(oa[nf][r] * inv, hh, ll);
            ctxh[orow + nf * 16 + l16] = hh;
            ctxl[orow + nf * 16 + l16] = ll;
        }
    }
}

// ---------------------------------------------------------------- router: fp64-accum logits, top-2, atomic slot assign
__global__ void k_router(const float* __restrict__ x2, const float* __restrict__ w2,
                         const float* __restrict__ rw, const float* __restrict__ bias,
                         int* __restrict__ cnt, int* __restrict__ te,
                         int* __restrict__ tpos, float* __restrict__ tw) {
    int wvi = threadIdx.x >> 6, lane = threadIdx.x & 63;
    int t = blockIdx.x * 4 + wvi;
    const float* xr = x2 + (long long)t * Dn;
    float xn[16];
    float ss = 0.f;
    #pragma unroll
    for (int j = 0; j < 16; j++) {
        float v = xr[lane + j * 64];
        ss += v * v;
        xn[j] = v * w2[lane + j * 64];
    }
    ss += __shfl_xor(ss, 1);  ss += __shfl_xor(ss, 2);  ss += __shfl_xor(ss, 4);
    ss += __shfl_xor(ss, 8);  ss += __shfl_xor(ss, 16); ss += __shfl_xor(ss, 32);
    float sc = rsqrtf(ss * (1.f / Dn) + 1e-6f);
    double lg[En];
    for (int e = 0; e < En; e++) {
        const float* rwe = rw + e * Dn;
        double a = 0.0;
        #pragma unroll
        for (int j = 0; j < 16; j++) a += (double)xn[j] * (double)rwe[lane + j * 64];
        a += __shfl_xor(a, 1);  a += __shfl_xor(a, 2);  a += __shfl_xor(a, 4);
        a += __shfl_xor(a, 8);  a += __shfl_xor(a, 16); a += __shfl_xor(a, 32);
        lg[e] = a;
    }
    if (lane == 0) {
        double g[En];
        for (int e = 0; e < En; e++)
            g[e] = 1.0 / (1.0 + exp(-((double)sc * lg[e] + (double)bias[e])));
        int e0 = 0; double b0 = g[0];
        for (int e = 1; e < En; e++) if (g[e] > b0) { b0 = g[e]; e0 = e; }
        int e1 = -1; double b1 = -1.0;
        for (int e = 0; e < En; e++) if (e != e0 && g[e] > b1) { b1 = g[e]; e1 = e; }
        double sum = b0 + b1 + 1e-9;
        int p0 = atomicAdd(&cnt[e0], 1);
        int p1 = atomicAdd(&cnt[e1], 1);
        te[2 * t] = e0;       te[2 * t + 1] = e1;
        tpos[2 * t] = p0;     tpos[2 * t + 1] = p1;
        tw[2 * t] = (float)(b0 / sum);
        tw[2 * t + 1] = (float)(b1 / sum);
    }
}

// ---------------------------------------------------------------- scan 16 counts
__global__ void k_scan(const int* __restrict__ cnt, int* __restrict__ offs) {
    if (threadIdx.x == 0) {
        int a = 0;
        for (int e = 0; e < En; e++) { offs[e] = a; a += cnt[e]; }
        offs[En] = a;
    }
}

// ---------------------------------------------------------------- gather h2 rows into expert-sorted xg
__global__ void k_gather(const u16* __restrict__ h2, u16* __restrict__ xg,
                         const int* __restrict__ te, const int* __restrict__ tpos,
                         const int* __restrict__ offs) {
    int p = blockIdx.x;
    int t = p >> 1;
    int slot = offs[te[p]] + tpos[p];
    const uint4* src = (const uint4*)(h2 + (long long)t * Dn);
    uint4* dst = (uint4*)(xg + (long long)slot * Dn);
    dst[threadIdx.x] = src[threadIdx.x];
}

// ---------------------------------------------------------------- combine: out = x2 + shared + w0*d0 + w1*d1
__global__ void k_combine(const float* __restrict__ x2, const u16* __restrict__ sho,
                          const u16* __restrict__ dwn, const int* __restrict__ te,
                          const int* __restrict__ tpos, const int* __restrict__ offs,
                          const float* __restrict__ tw, float* __restrict__ out) {
    int t = blockIdx.x;
    int s0 = offs[te[2 * t]] + tpos[2 * t];
    int s1 = offs[te[2 * t + 1]] + tpos[2 * t + 1];
    float w0 = tw[2 * t], w1 = tw[2 * t + 1];
    int i = threadIdx.x;
    float4 xv = ((const float4*)(x2 + (long long)t * Dn))[i];
    uint2 shv = ((const uint2*)(sho + (long long)t * Dn))[i];
    uint2 dv0 = ((const uint2*)(dwn + (long long)s0 * Dn))[i];
    uint2 dv1 = ((const uint2*)(dwn + (long long)s1 * Dn))[i];
    u16 s4[4], a4[4], b4[4];
    *(uint2*)s4 = shv; *(uint2*)a4 = dv0; *(uint2*)b4 = dv1;
    float4 o;
    o.x = xv.x + u2f(s4[0]) + w0 * u2f(a4[0]) + w1 * u2f(b4[0]);
    o.y = xv.y + u2f(s4[1]) + w0 * u2f(a4[1]) + w1 * u2f(b4[1]);
    o.z = xv.z + u2f(s4[2]) + w0 * u2f(a4[2]) + w1 * u2f(b4[2]);
    o.w = xv.w + u2f(s4[3]) + w0 * u2f(a4[3]) + w1 * u2f(b4[3]);
    ((float4*)(out + (long long)t * Dn))[i] = o;
}

// ---------------------------------------------------------------- launch
extern "C" void kernel_launch(void* const* d_in, const int* in_sizes, int n_in,
                              void* d_out, int out_size, void* d_ws, size_t ws_size,
                              hipStream_t stream) {
    const float* x     = (const float*)d_in[0];
    const float* n1w   = (const float*)d_in[1];
    const float* wq    = (const float*)d_in[2];
    const float* wk    = (const float*)d_in[3];
    const float* wvp   = (const float*)d_in[4];
    const float* wo    = (const float*)d_in[5];
    const float* n2w   = (const float*)d_in[6];
    const float* rw    = (const float*)d_in[7];
    const float* ebias = (const float*)d_in[8];
    const float* sg    = (const float*)d_in[9];
    const float* su    = (const float*)d_in[10];
    const float* sd    = (const float*)d_in[11];
    const float* eg    = (const float*)d_in[12];
    const float* eu    = (const float*)d_in[13];
    const float* ed    = (const float*)d_in[14];

    char* ws = (char*)d_ws;
    // layout (bytes), phase-aliased:
    //   [0,16M)      h1h (P1-P2)   -> sho bf16 (P6-P7)
    //   [16M,32M)    h1l (P1-P2)   -> dwn bf16 [16M,48M) (P6-P7)
    //   [32M,80M)    qkv u16 (P2-P3) -> xg [32M,64M) (P5-P6)
    //   [80M,96M)    ctxh (P3-P4)  -> acts bf16 (P6)
    //   [96M,112M)   ctxl (P3-P4)  -> actr bf16 [96M,128M) (P6)
    //   [128M,160M)  x2 fp32 (P4-P7)
    //   [160M,176M)  w-split hi/lo (P1-P4) -> h2 bf16 (P5-P6)
    //   [176M,...)   meta + rope tables
    u16*   h1h  = (u16*)(ws + 0);
    u16*   h1l  = (u16*)(ws + 16777216);
    u16*   sho  = (u16*)(ws + 0);
    u16*   dwn  = (u16*)(ws + 16777216);
    u16*   qkv  = (u16*)(ws + 33554432);
    u16*   xg   = (u16*)(ws + 33554432);
    u16*   ctxh = (u16*)(ws + 83886080);
    u16*   ctxl = (u16*)(ws + 100663296);
    u16*   acts = (u16*)(ws + 83886080);
    u16*   actr = (u16*)(ws + 100663296);
    float* x2   = (float*)(ws + 134217728);
    u16*   wh   = (u16*)(ws + 167772160);   // 4 mats x 1M u16 (wq,wk,wv,wo)
    u16*   wl   = (u16*)(ws + 176160768);
    u16*   h2   = (u16*)(ws + 167772160);   // after wo-gemm done
    char*  meta = ws + 184549376;
    int*   cnt  = (int*)(meta);
    int*   offs = (int*)(meta + 256);
    int*   te   = (int*)(meta + 512);
    int*   tpos = (int*)(meta + 512 + 65536);
    float* tw   = (float*)(meta + 512 + 131072);
    float* ct   = (float*)(meta + 262144);
    float* st   = (float*)(meta + 524288);
    float* out  = (float*)d_out;

    k_zero<<<1, 64, 0, stream>>>(cnt);
    k_ropetab<<<256, 256, 0, stream>>>(ct, st);
    k_rmsnorm<2><<<Tn, 256, 0, stream>>>(x, n1w, h1h, h1l);
    k_splitw4<<<dim3(1024, 4), 256, 0, stream>>>(wq, wk, wvp, wo, wh, wl);
    dim3 g32(8, 64, 1);
    // Q, K with fused RoPE; V plain; all -> f16 qkv
    k_gemm32s<0><<<g32, 256, 0, stream>>>(h1h, h1l, wh,           wl,           qkv, nullptr, ct, st, Dn, 3072, 0);
    k_gemm32s<0><<<g32, 256, 0, stream>>>(h1h, h1l, wh + 1048576, wl + 1048576, qkv, nullptr, ct, st, Dn, 3072, 1024);
    k_gemm32s<1><<<g32, 256, 0, stream>>>(h1h, h1l, wh + 2097152, wl + 2097152, qkv, nullptr, ct, st, Dn, 3072, 2048);
    k_attn16<<<dim3(32, 64), 256, 0, stream>>>(qkv, ctxh, ctxl);
    k_gemm32s<2><<<g32, 256, 0, stream>>>(ctxh, ctxl, wh + 3145728, wl + 3145728, x2, x, ct, st, Dn, 1024, 0);
    k_rmsnorm<1><<<Tn, 256, 0, stream>>>(x2, n2w, h2, nullptr);
    k_router<<<Tn / 4, 256, 0, stream>>>(x2, n2w, rw, ebias, cnt, te, tpos, tw);
    k_scan<<<1, 64, 0, stream>>>(cnt, offs);
    k_gather<<<Tn * 2, 128, 0, stream>>>(h2, xg, te, tpos, offs);
    // shared expert: gate+up fused, then down (bf16)
    k_gemm<64, 2, true, 2, false><<<dim3(16, 64, 1), 256, 0, stream>>>(h2, sg, su, acts, Tn, Dn, In, nullptr, 0);
    k_gemm<128, 4, false, 0, false><<<dim3(8, 64, 1), 256, 0, stream>>>(acts, sd, nullptr, sho, Tn, In, Dn, nullptr, 0);
    // routed experts: grouped gate+up fused, grouped down (bf16)
    k_gemm<64, 2, true, 2, true><<<dim3(16, 64, En), 256, 0, stream>>>(xg, eg, eu, actr, 0, Dn, In, offs, (long long)In * Dn);
    k_gemm<128, 4, false, 0, true><<<dim3(8, 64, En), 256, 0, stream>>>(actr, ed, nullptr, dwn, 0, In, Dn, offs, (long long)Dn * In);
    k_combine<<<Tn, 256, 0, stream>>>(x2, sho, dwn, te, tpos, offs, tw, out);
}